// Round 1
// baseline (587.862 us; speedup 1.0000x reference)
//
#include <hip/hip_runtime.h>
#include <hip/hip_bf16.h>
#include <stdint.h>

// B=8, S=2048, D=512, H=2, hd=256. All dims hardcoded.
// Pipeline:
//   f2b converts -> proj GEMMs (bf16) -> gate -> QKV GEMMs -> V transpose
//   -> flash attention (both directions) -> gate-mix -> final GEMM (+residual, f32 out)

typedef __bf16 bf16_t;
typedef __bf16 bf16x8 __attribute__((ext_vector_type(8)));
typedef float f32x4 __attribute__((ext_vector_type(4)));

typedef void gvoid_t __attribute__((address_space(1)));
typedef void svoid_t __attribute__((address_space(3)));

__device__ inline void gload16(const void* g, void* l) {
    __builtin_amdgcn_global_load_lds((gvoid_t*)g, (svoid_t*)l, 16, 0, 0);
}

// ---------------- f32 -> bf16 convert ----------------
__global__ __launch_bounds__(256) void f2b_kernel(const float* __restrict__ in,
                                                  bf16_t* __restrict__ out, int n8) {
    int i = blockIdx.x * 256 + threadIdx.x;
    if (i >= n8) return;
    const float4* p = reinterpret_cast<const float4*>(in) + (size_t)i * 2;
    float4 a = p[0], b = p[1];
    bf16x8 o;
    o[0] = (bf16_t)a.x; o[1] = (bf16_t)a.y; o[2] = (bf16_t)a.z; o[3] = (bf16_t)a.w;
    o[4] = (bf16_t)b.x; o[5] = (bf16_t)b.y; o[6] = (bf16_t)b.z; o[7] = (bf16_t)b.w;
    reinterpret_cast<bf16x8*>(out)[i] = o;
}

// ---------------- GEMM: C = A @ B^T (+bias, + mode-specific epilogue) -------
// A: [M][K] bf16, B: [N][K] bf16. 128x128 tile, BK=64, 4 waves, 16x16x32 MFMA.
// MODE 0: store bf16 (acc+bias)
// MODE 1: store bf16 (acc+bias) * (col<512 ? 1/16 : 1)      (QKV, q-scaling)
// MODE 2: store f32  acc+bias + 0.5*(r1+r2)                 (final out-proj)
template <int MODE>
__global__ __launch_bounds__(256) void gemm_bt(const bf16_t* __restrict__ A,
                                               const bf16_t* __restrict__ Bw,
                                               const float* __restrict__ bias,
                                               void* __restrict__ Cout,
                                               const bf16_t* __restrict__ r1,
                                               const bf16_t* __restrict__ r2,
                                               int M, int N, int K) {
    __shared__ __align__(16) bf16_t As[128][64];
    __shared__ __align__(16) bf16_t Bs[128][64];
    const int tid = threadIdx.x, lane = tid & 63, w = tid >> 6;
    const int l16 = lane & 15, l4 = lane >> 4;
    const int wm = w >> 1, wn = w & 1;
    const size_t a0 = (size_t)blockIdx.y * 128;
    const size_t b0 = (size_t)blockIdx.x * 128;
    f32x4 acc[4][4] = {};
    const int srow = w * 32 + (lane >> 3);
    const int scol = (lane & 7) * 8;
    for (int kt = 0; kt < K; kt += 64) {
        __syncthreads();
#pragma unroll
        for (int i = 0; i < 4; ++i) {
            gload16(A + (a0 + srow + i * 8) * (size_t)K + kt + scol, &As[w * 32 + i * 8][0]);
            gload16(Bw + (b0 + srow + i * 8) * (size_t)K + kt + scol, &Bs[w * 32 + i * 8][0]);
        }
        __syncthreads();
#pragma unroll
        for (int kk = 0; kk < 2; ++kk) {
            bf16x8 af[4], bfr[4];
#pragma unroll
            for (int mi = 0; mi < 4; ++mi)
                af[mi] = *reinterpret_cast<const bf16x8*>(&As[wm * 64 + mi * 16 + l16][kk * 32 + l4 * 8]);
#pragma unroll
            for (int ni = 0; ni < 4; ++ni)
                bfr[ni] = *reinterpret_cast<const bf16x8*>(&Bs[wn * 64 + ni * 16 + l16][kk * 32 + l4 * 8]);
#pragma unroll
            for (int mi = 0; mi < 4; ++mi)
#pragma unroll
                for (int ni = 0; ni < 4; ++ni)
                    acc[mi][ni] = __builtin_amdgcn_mfma_f32_16x16x32_bf16(af[mi], bfr[ni], acc[mi][ni], 0, 0, 0);
        }
    }
#pragma unroll
    for (int mi = 0; mi < 4; ++mi) {
#pragma unroll
        for (int ni = 0; ni < 4; ++ni) {
            int col = (int)b0 + wn * 64 + ni * 16 + l16;
            float bs = bias[col];
#pragma unroll
            for (int r = 0; r < 4; ++r) {
                int row = (int)a0 + wm * 64 + mi * 16 + l4 * 4 + r;
                float v = acc[mi][ni][r] + bs;
                size_t idx = (size_t)row * N + col;
                if (MODE == 0) {
                    ((bf16_t*)Cout)[idx] = (bf16_t)v;
                } else if (MODE == 1) {
                    if (col < 512) v *= 0.0625f;
                    ((bf16_t*)Cout)[idx] = (bf16_t)v;
                } else {
                    ((float*)Cout)[idx] = v + 0.5f * ((float)r1[idx] + (float)r2[idx]);
                }
            }
        }
    }
}

// ---------------- gate = sigmoid(sum(rgb_p*event_p, axis=-1)) ----------------
__global__ __launch_bounds__(256) void gate_kernel(const bf16_t* __restrict__ rp,
                                                   const bf16_t* __restrict__ ep,
                                                   float* __restrict__ gate) {
    int row = blockIdx.x * 4 + (threadIdx.x >> 6);
    int lane = threadIdx.x & 63;
    bf16x8 a = reinterpret_cast<const bf16x8*>(rp + (size_t)row * 512)[lane];
    bf16x8 b = reinterpret_cast<const bf16x8*>(ep + (size_t)row * 512)[lane];
    float s = 0.f;
#pragma unroll
    for (int j = 0; j < 8; ++j) s += (float)a[j] * (float)b[j];
#pragma unroll
    for (int off = 32; off; off >>= 1) s += __shfl_xor(s, off, 64);
    if (lane == 0) gate[row] = 1.f / (1.f + __expf(-s));
}

// ---------------- V transpose: qkv v-part -> Vt[(b*2+h)*256 + d][2048] -------
__global__ __launch_bounds__(256) void vtrans_kernel(const bf16_t* __restrict__ qkv_evt,
                                                     const bf16_t* __restrict__ qkv_rgb,
                                                     bf16_t* __restrict__ vt0,
                                                     bf16_t* __restrict__ vt1) {
    __shared__ __align__(16) unsigned short tile[64][72];
    int bx = blockIdx.x;
    int dir = bx >> 11;
    int idx = bx & 2047;
    int bh = idx >> 7;
    int st = (idx >> 2) & 31;
    int dt = idx & 3;
    int b = bh >> 1, h = bh & 1;
    const bf16_t* src = dir ? qkv_rgb : qkv_evt;
    bf16_t* dst = dir ? vt1 : vt0;
    int t = threadIdx.x;
    int r = t >> 2, cc = (t & 3) * 16;
    const bf16_t* sp = src + ((size_t)(b * 2048 + st * 64 + r)) * 1536 + 1024 + h * 256 + dt * 64 + cc;
    uint4 x0 = *reinterpret_cast<const uint4*>(sp);
    uint4 x1 = *reinterpret_cast<const uint4*>(sp + 8);
    *reinterpret_cast<uint4*>(&tile[r][cc]) = x0;
    *reinterpret_cast<uint4*>(&tile[r][cc + 8]) = x1;
    __syncthreads();
    int dl = t >> 2, sc = (t & 3) * 16;
    __align__(16) unsigned short o[16];
#pragma unroll
    for (int j = 0; j < 16; ++j) o[j] = tile[sc + j][dl];
    bf16_t* dp = dst + ((size_t)((b * 2 + h) * 256 + dt * 64 + dl)) * 2048 + st * 64 + sc;
    *reinterpret_cast<uint4*>(dp) = *reinterpret_cast<uint4*>(&o[0]);
    *reinterpret_cast<uint4*>(dp + 8) = *reinterpret_cast<uint4*>(&o[8]);
}

// ---------------- flash attention ----------------
// grid: dir(2) x b(8) x h(2) x qb(32), 256 threads (4 waves), wave = 16 q rows.
// Q in regs; K,V LDS tiles (XOR-swizzled via pre-swizzled global src); P via LDS.
__global__ __launch_bounds__(256) void attn_kernel(const bf16_t* __restrict__ qkv_rgb,
                                                   const bf16_t* __restrict__ qkv_evt,
                                                   const bf16_t* __restrict__ vt0,
                                                   const bf16_t* __restrict__ vt1,
                                                   bf16_t* __restrict__ out0,
                                                   bf16_t* __restrict__ out1) {
    __shared__ __align__(16) bf16_t Ks[64][256];
    __shared__ __align__(16) bf16_t Vts[256][64];
    __shared__ __align__(16) bf16_t Ps[4][16][72];
    int bx = blockIdx.x;
    int dir = bx >> 9;
    int idx = bx & 511;
    int b = idx >> 6;
    int h = (idx >> 5) & 1;
    int qb = idx & 31;
    const bf16_t* Qsrc = dir ? qkv_evt : qkv_rgb;
    const bf16_t* Ksrc = dir ? qkv_rgb : qkv_evt;
    const bf16_t* Vsrc = dir ? vt1 : vt0;
    bf16_t* osrc = dir ? out1 : out0;
    const int tid = threadIdx.x, lane = tid & 63, w = tid >> 6;
    const int l16 = lane & 15, l4 = lane >> 4;

    const bf16_t* qp = Qsrc + ((size_t)(b * 2048 + qb * 64 + w * 16 + l16)) * 1536 + h * 256;
    bf16x8 qf[8];
#pragma unroll
    for (int dc = 0; dc < 8; ++dc)
        qf[dc] = *reinterpret_cast<const bf16x8*>(qp + dc * 32 + l4 * 8);

    f32x4 o[16] = {};
    float mrun[4] = {-1e30f, -1e30f, -1e30f, -1e30f};
    float lrun[4] = {0.f, 0.f, 0.f, 0.f};

    const int krow2 = lane >> 5;  // K staging: 2 rows / waveload
    const int ku = lane & 31;
    const int vrow8 = lane >> 3;  // V staging: 8 rows / waveload
    const int vu = lane & 7;

    for (int kt = 0; kt < 32; ++kt) {
        __syncthreads();
#pragma unroll
        for (int i = 0; i < 8; ++i) {
            int row = (w * 8 + i) * 2 + krow2;
            int ud = ku ^ (row & 7);
            gload16(Ksrc + ((size_t)(b * 2048 + kt * 64 + row)) * 1536 + 512 + h * 256 + ud * 8,
                    &Ks[(w * 8 + i) * 2][0]);
            int vrow = (w * 8 + i) * 8 + vrow8;
            int vud = vu ^ (vrow & 7);
            gload16(Vsrc + ((size_t)((b * 2 + h) * 256 + vrow)) * 2048 + kt * 64 + vud * 8,
                    &Vts[(w * 8 + i) * 8][0]);
        }
        __syncthreads();

        f32x4 sa[4] = {};
#pragma unroll
        for (int n = 0; n < 4; ++n) {
            int roww = n * 16 + l16;
#pragma unroll
            for (int dc = 0; dc < 8; ++dc) {
                const bf16x8 kf = *reinterpret_cast<const bf16x8*>(
                    &Ks[0][0] + roww * 256 + (((dc * 4 + l4) ^ (l16 & 7)) * 8));
                sa[n] = __builtin_amdgcn_mfma_f32_16x16x32_bf16(qf[dc], kf, sa[n], 0, 0, 0);
            }
        }
#pragma unroll
        for (int r = 0; r < 4; ++r) {
            float mx = fmaxf(fmaxf(sa[0][r], sa[1][r]), fmaxf(sa[2][r], sa[3][r]));
#pragma unroll
            for (int off = 1; off <= 8; off <<= 1) mx = fmaxf(mx, __shfl_xor(mx, off, 64));
            float mnew = fmaxf(mrun[r], mx);
            float sc = __expf(mrun[r] - mnew);
            mrun[r] = mnew;
            float p0 = __expf(sa[0][r] - mnew);
            float p1 = __expf(sa[1][r] - mnew);
            float p2 = __expf(sa[2][r] - mnew);
            float p3 = __expf(sa[3][r] - mnew);
            float rs = p0 + p1 + p2 + p3;
#pragma unroll
            for (int off = 1; off <= 8; off <<= 1) rs += __shfl_xor(rs, off, 64);
            lrun[r] = lrun[r] * sc + rs;
#pragma unroll
            for (int dt = 0; dt < 16; ++dt) o[dt][r] *= sc;
            int prow = l4 * 4 + r;
            Ps[w][prow][0 * 16 + l16] = (bf16_t)p0;
            Ps[w][prow][1 * 16 + l16] = (bf16_t)p1;
            Ps[w][prow][2 * 16 + l16] = (bf16_t)p2;
            Ps[w][prow][3 * 16 + l16] = (bf16_t)p3;
        }
        __syncthreads();
#pragma unroll
        for (int kc = 0; kc < 2; ++kc) {
            const bf16x8 pf = *reinterpret_cast<const bf16x8*>(&Ps[w][l16][kc * 32 + l4 * 8]);
#pragma unroll
            for (int dt = 0; dt < 16; ++dt) {
                const bf16x8 vf = *reinterpret_cast<const bf16x8*>(
                    &Vts[0][0] + (dt * 16 + l16) * 64 + (((kc * 4 + l4) ^ (l16 & 7)) * 8));
                o[dt] = __builtin_amdgcn_mfma_f32_16x16x32_bf16(pf, vf, o[dt], 0, 0, 0);
            }
        }
    }
#pragma unroll
    for (int r = 0; r < 4; ++r) {
        float inv = 1.0f / lrun[r];
        size_t rowb = ((size_t)(b * 2048 + qb * 64 + w * 16 + l4 * 4 + r)) * 512 + h * 256;
#pragma unroll
        for (int dt = 0; dt < 16; ++dt)
            osrc[rowb + dt * 16 + l16] = (bf16_t)(o[dt][r] * inv);
    }
}

// ---------------- mix: gate*attn1 + (1-gate)*attn2 -> bf16 ----------------
__global__ __launch_bounds__(256) void mix_kernel(const bf16_t* __restrict__ a1,
                                                  const bf16_t* __restrict__ a2,
                                                  const float* __restrict__ gate,
                                                  bf16_t* __restrict__ outm) {
    int i = blockIdx.x * 256 + threadIdx.x;
    int m = i >> 6;
    float g = gate[m];
    bf16x8 x = reinterpret_cast<const bf16x8*>(a1)[i];
    bf16x8 y = reinterpret_cast<const bf16x8*>(a2)[i];
    bf16x8 o;
#pragma unroll
    for (int j = 0; j < 8; ++j) o[j] = (bf16_t)(g * (float)x[j] + (1.f - g) * (float)y[j]);
    reinterpret_cast<bf16x8*>(outm)[i] = o;
}

extern "C" void kernel_launch(void* const* d_in, const int* in_sizes, int n_in,
                              void* d_out, int out_size, void* d_ws, size_t ws_size,
                              hipStream_t stream) {
    const float* rgb = (const float*)d_in[0];
    const float* event = (const float*)d_in[1];
    const float* w_rgb = (const float*)d_in[2];
    const float* b_rgb = (const float*)d_in[3];
    const float* w_event = (const float*)d_in[4];
    const float* b_event = (const float*)d_in[5];
    const float* w_in = (const float*)d_in[6];
    const float* b_in = (const float*)d_in[7];
    const float* w_out = (const float*)d_in[8];
    const float* b_out = (const float*)d_in[9];
    float* out = (float*)d_out;

    const int M = 16384;  // B*S
    const size_t SZ = (size_t)M * 512 * 2;  // 16 MiB (bf16 [16384][512])
    char* ws = (char*)d_ws;
    bf16_t* wrgb_bf = (bf16_t*)(ws + 0);
    bf16_t* wevt_bf = (bf16_t*)(ws + 524288);
    bf16_t* wout_bf = (bf16_t*)(ws + 1048576);
    bf16_t* win_bf = (bf16_t*)(ws + 1572864);
    float* gate = (float*)(ws + 3145728);
    bf16_t* bufA = (bf16_t*)(ws + 4194304);           // rgb_bf16 -> attn1
    bf16_t* bufB = (bf16_t*)(ws + 4194304 + SZ);      // event_bf16 -> attn2
    bf16_t* rgbp = (bf16_t*)(ws + 4194304 + 2 * SZ);
    bf16_t* evtp = (bf16_t*)(ws + 4194304 + 3 * SZ);
    bf16_t* qkvr = (bf16_t*)(ws + 4194304 + 4 * SZ);  // 3*SZ
    bf16_t* qkve = (bf16_t*)(ws + 4194304 + 7 * SZ);  // 3*SZ
    bf16_t* vt0 = (bf16_t*)(ws + 4194304 + 10 * SZ);
    bf16_t* vt1 = (bf16_t*)(ws + 4194304 + 11 * SZ);
    bf16_t* mixed = qkvr;  // reuse (dead after attention)

    dim3 blk(256);
    // converts
    f2b_kernel<<<4096, blk, 0, stream>>>(rgb, bufA, M * 512 / 8);
    f2b_kernel<<<4096, blk, 0, stream>>>(event, bufB, M * 512 / 8);
    f2b_kernel<<<128, blk, 0, stream>>>(w_rgb, wrgb_bf, 512 * 512 / 8);
    f2b_kernel<<<128, blk, 0, stream>>>(w_event, wevt_bf, 512 * 512 / 8);
    f2b_kernel<<<384, blk, 0, stream>>>(w_in, win_bf, 1536 * 512 / 8);
    f2b_kernel<<<128, blk, 0, stream>>>(w_out, wout_bf, 512 * 512 / 8);
    // input projections
    gemm_bt<0><<<dim3(4, 128), blk, 0, stream>>>(bufA, wrgb_bf, b_rgb, rgbp, nullptr, nullptr, M, 512, 512);
    gemm_bt<0><<<dim3(4, 128), blk, 0, stream>>>(bufB, wevt_bf, b_event, evtp, nullptr, nullptr, M, 512, 512);
    // gate
    gate_kernel<<<4096, blk, 0, stream>>>(rgbp, evtp, gate);
    // QKV projections (q-scale folded in)
    gemm_bt<1><<<dim3(12, 128), blk, 0, stream>>>(rgbp, win_bf, b_in, qkvr, nullptr, nullptr, M, 1536, 512);
    gemm_bt<1><<<dim3(12, 128), blk, 0, stream>>>(evtp, win_bf, b_in, qkve, nullptr, nullptr, M, 1536, 512);
    // V transpose for both directions
    vtrans_kernel<<<4096, blk, 0, stream>>>(qkve, qkvr, vt0, vt1);
    // attention both directions
    attn_kernel<<<1024, blk, 0, stream>>>(qkvr, qkve, vt0, vt1, bufA, bufB);
    // gated mix
    mix_kernel<<<4096, blk, 0, stream>>>(bufA, bufB, gate, mixed);
    // final projection + residual, f32 out
    gemm_bt<2><<<dim3(4, 128), blk, 0, stream>>>(mixed, wout_bf, b_out, out, rgbp, evtp, M, 512, 512);
}

// Round 2
// 422.963 us; speedup vs baseline: 1.3899x; 1.3899x over previous
//
#include <hip/hip_runtime.h>
#include <hip/hip_bf16.h>
#include <stdint.h>

// B=8, S=2048, D=512, H=2, hd=256. All dims hardcoded.
// Pipeline:
//   f2b converts -> proj GEMMs (bf16) -> gate -> QKV GEMMs -> V tile-layout transpose
//   -> flash attention v2 (swapped-QK, in-reg softmax, 32x32 MFMA) -> gate-mix
//   -> final GEMM (+residual, f32 out)

typedef __bf16 bf16_t;
typedef __bf16 bf16x8 __attribute__((ext_vector_type(8)));
typedef float f32x4 __attribute__((ext_vector_type(4)));
typedef float f32x16 __attribute__((ext_vector_type(16)));
typedef unsigned int u32;

typedef void gvoid_t __attribute__((address_space(1)));
typedef void svoid_t __attribute__((address_space(3)));

__device__ inline void gload16(const void* g, void* l) {
    __builtin_amdgcn_global_load_lds((gvoid_t*)g, (svoid_t*)l, 16, 0, 0);
}

__device__ inline u32 cvtpk_bf16(float lo, float hi) {
    u32 r;
    asm("v_cvt_pk_bf16_f32 %0, %1, %2" : "=v"(r) : "v"(lo), "v"(hi));
    return r;
}

// ---------------- f32 -> bf16 convert ----------------
__global__ __launch_bounds__(256) void f2b_kernel(const float* __restrict__ in,
                                                  bf16_t* __restrict__ out, int n8) {
    int i = blockIdx.x * 256 + threadIdx.x;
    if (i >= n8) return;
    const float4* p = reinterpret_cast<const float4*>(in) + (size_t)i * 2;
    float4 a = p[0], b = p[1];
    bf16x8 o;
    o[0] = (bf16_t)a.x; o[1] = (bf16_t)a.y; o[2] = (bf16_t)a.z; o[3] = (bf16_t)a.w;
    o[4] = (bf16_t)b.x; o[5] = (bf16_t)b.y; o[6] = (bf16_t)b.z; o[7] = (bf16_t)b.w;
    reinterpret_cast<bf16x8*>(out)[i] = o;
}

// ---------------- GEMM: C = A @ B^T (+bias, + mode-specific epilogue) -------
// A: [M][K] bf16, B: [N][K] bf16. 128x128 tile, BK=64, 4 waves, 16x16x32 MFMA.
// MODE 0: store bf16 (acc+bias)
// MODE 1: store bf16 (acc+bias) * (col<512 ? 1/16 : 1)      (QKV, q-scaling)
// MODE 2: store f32  acc+bias + 0.5*(r1+r2)                 (final out-proj)
template <int MODE>
__global__ __launch_bounds__(256) void gemm_bt(const bf16_t* __restrict__ A,
                                               const bf16_t* __restrict__ Bw,
                                               const float* __restrict__ bias,
                                               void* __restrict__ Cout,
                                               const bf16_t* __restrict__ r1,
                                               const bf16_t* __restrict__ r2,
                                               int M, int N, int K) {
    __shared__ __align__(16) bf16_t As[128][64];
    __shared__ __align__(16) bf16_t Bs[128][64];
    const int tid = threadIdx.x, lane = tid & 63, w = tid >> 6;
    const int l16 = lane & 15, l4 = lane >> 4;
    const int wm = w >> 1, wn = w & 1;
    const size_t a0 = (size_t)blockIdx.y * 128;
    const size_t b0 = (size_t)blockIdx.x * 128;
    f32x4 acc[4][4] = {};
    const int srow = w * 32 + (lane >> 3);
    const int scol = (lane & 7) * 8;
    for (int kt = 0; kt < K; kt += 64) {
        __syncthreads();
#pragma unroll
        for (int i = 0; i < 4; ++i) {
            gload16(A + (a0 + srow + i * 8) * (size_t)K + kt + scol, &As[w * 32 + i * 8][0]);
            gload16(Bw + (b0 + srow + i * 8) * (size_t)K + kt + scol, &Bs[w * 32 + i * 8][0]);
        }
        __syncthreads();
#pragma unroll
        for (int kk = 0; kk < 2; ++kk) {
            bf16x8 af[4], bfr[4];
#pragma unroll
            for (int mi = 0; mi < 4; ++mi)
                af[mi] = *reinterpret_cast<const bf16x8*>(&As[wm * 64 + mi * 16 + l16][kk * 32 + l4 * 8]);
#pragma unroll
            for (int ni = 0; ni < 4; ++ni)
                bfr[ni] = *reinterpret_cast<const bf16x8*>(&Bs[wn * 64 + ni * 16 + l16][kk * 32 + l4 * 8]);
#pragma unroll
            for (int mi = 0; mi < 4; ++mi)
#pragma unroll
                for (int ni = 0; ni < 4; ++ni)
                    acc[mi][ni] = __builtin_amdgcn_mfma_f32_16x16x32_bf16(af[mi], bfr[ni], acc[mi][ni], 0, 0, 0);
        }
    }
#pragma unroll
    for (int mi = 0; mi < 4; ++mi) {
#pragma unroll
        for (int ni = 0; ni < 4; ++ni) {
            int col = (int)b0 + wn * 64 + ni * 16 + l16;
            float bs = bias[col];
#pragma unroll
            for (int r = 0; r < 4; ++r) {
                int row = (int)a0 + wm * 64 + mi * 16 + l4 * 4 + r;
                float v = acc[mi][ni][r] + bs;
                size_t idx = (size_t)row * N + col;
                if (MODE == 0) {
                    ((bf16_t*)Cout)[idx] = (bf16_t)v;
                } else if (MODE == 1) {
                    if (col < 512) v *= 0.0625f;
                    ((bf16_t*)Cout)[idx] = (bf16_t)v;
                } else {
                    ((float*)Cout)[idx] = v + 0.5f * ((float)r1[idx] + (float)r2[idx]);
                }
            }
        }
    }
}

// ---------------- gate = sigmoid(sum(rgb_p*event_p, axis=-1)) ----------------
__global__ __launch_bounds__(256) void gate_kernel(const bf16_t* __restrict__ rp,
                                                   const bf16_t* __restrict__ ep,
                                                   float* __restrict__ gate) {
    int row = blockIdx.x * 4 + (threadIdx.x >> 6);
    int lane = threadIdx.x & 63;
    bf16x8 a = reinterpret_cast<const bf16x8*>(rp + (size_t)row * 512)[lane];
    bf16x8 b = reinterpret_cast<const bf16x8*>(ep + (size_t)row * 512)[lane];
    float s = 0.f;
#pragma unroll
    for (int j = 0; j < 8; ++j) s += (float)a[j] * (float)b[j];
#pragma unroll
    for (int off = 32; off; off >>= 1) s += __shfl_xor(s, off, 64);
    if (lane == 0) gate[row] = 1.f / (1.f + __expf(-s));
}

// ---------------- V layout transform ----------------
// qkv V-part [seq][d] -> Vt[(bh*32+kt)*8 + kchunk][d 0..255][8 k-elems]
// so attention can stage/read the PV B-operand fully linearly (no bank conflicts).
__global__ __launch_bounds__(256) void vtrans_kernel(const bf16_t* __restrict__ qkv_evt,
                                                     const bf16_t* __restrict__ qkv_rgb,
                                                     bf16_t* __restrict__ vt0,
                                                     bf16_t* __restrict__ vt1) {
    __shared__ bf16_t tile[64][256];
    int bid = blockIdx.x;
    int dir = bid >> 9;
    int rem = bid & 511;
    int bh = rem >> 5, kt = rem & 31;
    int b = bh >> 1, h = bh & 1;
    const bf16_t* src = dir ? qkv_rgb : qkv_evt;
    bf16_t* dst = dir ? vt1 : vt0;
    int t = threadIdx.x;
    int tl = t & 31, th = t >> 5;
#pragma unroll
    for (int it = 0; it < 8; ++it) {
        int r = it * 8 + th;
        bf16x8 v = *reinterpret_cast<const bf16x8*>(
            src + ((size_t)(b * 2048 + kt * 64 + r)) * 1536 + 1024 + h * 256 + tl * 8);
        *reinterpret_cast<bf16x8*>(&tile[r][tl * 8]) = v;
    }
    __syncthreads();
    int d = t;
    size_t base = ((size_t)(bh * 32 + kt)) * 8;
#pragma unroll
    for (int kc = 0; kc < 8; ++kc) {
        bf16x8 ov;
#pragma unroll
        for (int e = 0; e < 8; ++e) ov[e] = tile[kc * 8 + e][d];
        *reinterpret_cast<bf16x8*>(dst + (base + kc) * 2048 + d * 8) = ov;
    }
}

// ---------------- flash attention v2 ----------------
// grid 512: bid = qb*32 + dir*16 + bh. 256 threads (4 waves), wave owns 32 q rows.
// Swapped QK^T (mfma(K,Q)) -> lane-local P row; in-register softmax (T12) with
// defer-max (T13); K LDS XOR-swizzled via pre-swizzled global src (G21);
// V in k-chunk-major tiles (conflict-free, no swizzle).
__global__ __launch_bounds__(256, 2) void attn_kernel(const bf16_t* __restrict__ qkv_rgb,
                                                      const bf16_t* __restrict__ qkv_evt,
                                                      const bf16_t* __restrict__ vt0,
                                                      const bf16_t* __restrict__ vt1,
                                                      bf16_t* __restrict__ out0,
                                                      bf16_t* __restrict__ out1) {
    __shared__ __align__(16) bf16_t KsL[64 * 256];       // [k][d], chunk-xor-swizzled
    __shared__ __align__(16) bf16_t VsL[8 * 256 * 8];    // [kchunk][d][8k]
    const int bid = blockIdx.x;
    const int qb = bid >> 5;
    const int combo = bid & 31;
    const int dir = combo >> 4;
    const int bh = combo & 15;
    const int b = bh >> 1, h = bh & 1;
    const bf16_t* Qsrc = dir ? qkv_evt : qkv_rgb;
    const bf16_t* Ksrc = dir ? qkv_rgb : qkv_evt;
    const bf16_t* Vtg = dir ? vt1 : vt0;
    bf16_t* osrc = dir ? out1 : out0;
    const int tid = threadIdx.x;
    const int w = tid >> 6, l = tid & 63;
    const int l31 = l & 31, hi = l >> 5;
    const int q0w = qb * 128 + w * 32;

    // Q fragments (B-operand): lane holds Q[q0w + (l&31)][dch*16 + hi*8 + j]
    const bf16_t* qp = Qsrc + ((size_t)(b * 2048 + q0w + l31)) * 1536 + h * 256 + hi * 8;
    bf16x8 qf[16];
#pragma unroll
    for (int dch = 0; dch < 16; ++dch)
        qf[dch] = *reinterpret_cast<const bf16x8*>(qp + dch * 16);

    f32x16 O[8] = {};
    float mrun = -1e30f, lrun = 0.f;

    // K staging offsets (fixed per thread): row w*16+i*2+hi, src chunk = l31 ^ (row&31)
    const bf16_t* Kbase = Ksrc + (size_t)b * 2048 * 1536 + 512 + h * 256;
    u32 koff[8];
#pragma unroll
    for (int i = 0; i < 8; ++i) {
        int row = w * 16 + i * 2 + hi;
        koff[i] = (u32)(row * 1536 + ((l31 ^ (row & 31)) * 8));
    }
    const bf16_t* Vbase = Vtg + ((size_t)bh * 32) * 8 * 2048 + (w * 64 + l) * 8;

    for (int kt = 0; kt < 32; ++kt) {
        __syncthreads();
#pragma unroll
        for (int i = 0; i < 8; ++i)
            gload16(Kbase + (size_t)kt * 64 * 1536 + koff[i], &KsL[(w * 16 + i * 2) * 256]);
#pragma unroll
        for (int i = 0; i < 8; ++i)
            gload16(Vbase + (size_t)kt * 16384 + i * 2048, &VsL[(i * 256 + w * 64) * 8]);
        __syncthreads();

        // QK^T (swapped): ST[k][q], A = K frags, B = Q frags
        f32x16 st0 = {}, st1 = {};
#pragma unroll
        for (int dch = 0; dch < 16; ++dch) {
            bf16x8 k0 = *reinterpret_cast<const bf16x8*>(
                &KsL[l31 * 256 + (((dch * 2 + hi) ^ l31) * 8)]);
            bf16x8 k1 = *reinterpret_cast<const bf16x8*>(
                &KsL[(32 + l31) * 256 + (((dch * 2 + hi) ^ l31) * 8)]);
            st0 = __builtin_amdgcn_mfma_f32_32x32x16_bf16(k0, qf[dch], st0, 0, 0, 0);
            st1 = __builtin_amdgcn_mfma_f32_32x32x16_bf16(k1, qf[dch], st1, 0, 0, 0);
        }

        // online softmax, lane-local (q = l&31); partner lane (^32) holds other k half
        float mx = -1e30f;
#pragma unroll
        for (int r = 0; r < 16; ++r) { mx = fmaxf(mx, st0[r]); mx = fmaxf(mx, st1[r]); }
        mx = fmaxf(mx, __shfl_xor(mx, 32, 64));
        if (__any(mx - mrun > 8.f)) {
            float mnew = fmaxf(mrun, mx);
            float sc = __expf(mrun - mnew);
            mrun = mnew;
            lrun *= sc;
#pragma unroll
            for (int r = 0; r < 16; ++r) {
                int qr = (r & 3) + 8 * (r >> 2) + 4 * hi;
                float scr = __shfl(sc, qr, 64);
#pragma unroll
                for (int g = 0; g < 8; ++g) O[g][r] *= scr;
            }
        }
        float lsum = 0.f;
        u32 W[16];
#pragma unroll
        for (int m = 0; m < 16; ++m) {
            float plo, phi_;
            if (m < 8) {
                int r = 2 * m;
                plo = __expf(st0[r] - mrun);
                phi_ = __expf(st0[r + 1] - mrun);
            } else {
                int r = 2 * m - 16;
                plo = __expf(st1[r] - mrun);
                phi_ = __expf(st1[r + 1] - mrun);
            }
            lsum += plo + phi_;
            W[m] = cvtpk_bf16(plo, phi_);
        }
        lsum += __shfl_xor(lsum, 32, 64);
        lrun += lsum;

        // PV: A = P (built in-register via 2 shfl_xor(32) per k-step), B = V
#pragma unroll
        for (int s = 0; s < 4; ++s) {
            u32 t0 = hi ? W[4 * s] : W[4 * s + 2];
            u32 t1 = hi ? W[4 * s + 1] : W[4 * s + 3];
            u32 r0 = (u32)__shfl_xor((int)t0, 32, 64);
            u32 r1 = (u32)__shfl_xor((int)t1, 32, 64);
            union { u32 uw[4]; bf16x8 v; } a;
            a.uw[0] = hi ? r0 : W[4 * s];
            a.uw[1] = hi ? r1 : W[4 * s + 1];
            a.uw[2] = hi ? W[4 * s + 2] : r0;
            a.uw[3] = hi ? W[4 * s + 3] : r1;
#pragma unroll
            for (int g = 0; g < 8; ++g) {
                bf16x8 vf = *reinterpret_cast<const bf16x8*>(
                    &VsL[((s * 2 + hi) * 256 + g * 32 + l31) * 8]);
                O[g] = __builtin_amdgcn_mfma_f32_32x32x16_bf16(a.v, vf, O[g], 0, 0, 0);
            }
        }
    }
    // epilogue: normalize (lrun broadcast per q-row) and store
#pragma unroll
    for (int r = 0; r < 16; ++r) {
        int qr = (r & 3) + 8 * (r >> 2) + 4 * hi;
        float linv = 1.0f / __shfl(lrun, qr, 64);
        size_t rowoff = ((size_t)(b * 2048 + q0w + qr)) * 512 + h * 256 + l31;
#pragma unroll
        for (int g = 0; g < 8; ++g)
            osrc[rowoff + g * 32] = (bf16_t)(O[g][r] * linv);
    }
}

// ---------------- mix: gate*attn1 + (1-gate)*attn2 -> bf16 ----------------
__global__ __launch_bounds__(256) void mix_kernel(const bf16_t* __restrict__ a1,
                                                  const bf16_t* __restrict__ a2,
                                                  const float* __restrict__ gate,
                                                  bf16_t* __restrict__ outm) {
    int i = blockIdx.x * 256 + threadIdx.x;
    int m = i >> 6;
    float g = gate[m];
    bf16x8 x = reinterpret_cast<const bf16x8*>(a1)[i];
    bf16x8 y = reinterpret_cast<const bf16x8*>(a2)[i];
    bf16x8 o;
#pragma unroll
    for (int j = 0; j < 8; ++j) o[j] = (bf16_t)(g * (float)x[j] + (1.f - g) * (float)y[j]);
    reinterpret_cast<bf16x8*>(outm)[i] = o;
}

extern "C" void kernel_launch(void* const* d_in, const int* in_sizes, int n_in,
                              void* d_out, int out_size, void* d_ws, size_t ws_size,
                              hipStream_t stream) {
    const float* rgb = (const float*)d_in[0];
    const float* event = (const float*)d_in[1];
    const float* w_rgb = (const float*)d_in[2];
    const float* b_rgb = (const float*)d_in[3];
    const float* w_event = (const float*)d_in[4];
    const float* b_event = (const float*)d_in[5];
    const float* w_in = (const float*)d_in[6];
    const float* b_in = (const float*)d_in[7];
    const float* w_out = (const float*)d_in[8];
    const float* b_out = (const float*)d_in[9];
    float* out = (float*)d_out;

    const int M = 16384;  // B*S
    const size_t SZ = (size_t)M * 512 * 2;  // 16 MiB (bf16 [16384][512])
    char* ws = (char*)d_ws;
    bf16_t* wrgb_bf = (bf16_t*)(ws + 0);
    bf16_t* wevt_bf = (bf16_t*)(ws + 524288);
    bf16_t* wout_bf = (bf16_t*)(ws + 1048576);
    bf16_t* win_bf = (bf16_t*)(ws + 1572864);
    float* gate = (float*)(ws + 3145728);
    bf16_t* bufA = (bf16_t*)(ws + 4194304);           // rgb_bf16 -> attn1
    bf16_t* bufB = (bf16_t*)(ws + 4194304 + SZ);      // event_bf16 -> attn2
    bf16_t* rgbp = (bf16_t*)(ws + 4194304 + 2 * SZ);
    bf16_t* evtp = (bf16_t*)(ws + 4194304 + 3 * SZ);
    bf16_t* qkvr = (bf16_t*)(ws + 4194304 + 4 * SZ);  // 3*SZ
    bf16_t* qkve = (bf16_t*)(ws + 4194304 + 7 * SZ);  // 3*SZ
    bf16_t* vt0 = (bf16_t*)(ws + 4194304 + 10 * SZ);
    bf16_t* vt1 = (bf16_t*)(ws + 4194304 + 11 * SZ);
    bf16_t* mixed = qkvr;  // reuse (dead after attention)

    dim3 blk(256);
    // converts
    f2b_kernel<<<4096, blk, 0, stream>>>(rgb, bufA, M * 512 / 8);
    f2b_kernel<<<4096, blk, 0, stream>>>(event, bufB, M * 512 / 8);
    f2b_kernel<<<128, blk, 0, stream>>>(w_rgb, wrgb_bf, 512 * 512 / 8);
    f2b_kernel<<<128, blk, 0, stream>>>(w_event, wevt_bf, 512 * 512 / 8);
    f2b_kernel<<<384, blk, 0, stream>>>(w_in, win_bf, 1536 * 512 / 8);
    f2b_kernel<<<128, blk, 0, stream>>>(w_out, wout_bf, 512 * 512 / 8);
    // input projections
    gemm_bt<0><<<dim3(4, 128), blk, 0, stream>>>(bufA, wrgb_bf, b_rgb, rgbp, nullptr, nullptr, M, 512, 512);
    gemm_bt<0><<<dim3(4, 128), blk, 0, stream>>>(bufB, wevt_bf, b_event, evtp, nullptr, nullptr, M, 512, 512);
    // gate
    gate_kernel<<<4096, blk, 0, stream>>>(rgbp, evtp, gate);
    // QKV projections (q-scale folded in)
    gemm_bt<1><<<dim3(12, 128), blk, 0, stream>>>(rgbp, win_bf, b_in, qkvr, nullptr, nullptr, M, 1536, 512);
    gemm_bt<1><<<dim3(12, 128), blk, 0, stream>>>(evtp, win_bf, b_in, qkve, nullptr, nullptr, M, 1536, 512);
    // V layout transform for both directions
    vtrans_kernel<<<1024, blk, 0, stream>>>(qkve, qkvr, vt0, vt1);
    // attention both directions
    attn_kernel<<<512, blk, 0, stream>>>(qkvr, qkve, vt0, vt1, bufA, bufB);
    // gated mix
    mix_kernel<<<4096, blk, 0, stream>>>(bufA, bufB, gate, mixed);
    // final projection + residual, f32 out
    gemm_bt<2><<<dim3(4, 128), blk, 0, stream>>>(mixed, wout_bf, b_out, out, rgbp, evtp, M, 512, 512);
}

// Round 3
// 374.109 us; speedup vs baseline: 1.5714x; 1.1306x over previous
//
#include <hip/hip_runtime.h>
#include <hip/hip_bf16.h>
#include <stdint.h>

// B=8, S=2048, D=512, H=2, hd=256. All dims hardcoded.
// Pipeline:
//   f2b converts -> proj GEMMs (bf16) -> gate -> QKV GEMM (writes Q compact,
//   K/V in pre-chunked attention-ready layouts) -> flash attention v3
//   (double-buffered, raw-barrier pipeline, zero-VALU LDS addressing)
//   -> gate-mix -> final GEMM (+residual, f32 out)

typedef __bf16 bf16_t;
typedef __bf16 bf16x8 __attribute__((ext_vector_type(8)));
typedef float f32x4 __attribute__((ext_vector_type(4)));
typedef float f32x16 __attribute__((ext_vector_type(16)));
typedef unsigned int u32;

typedef void gvoid_t __attribute__((address_space(1)));
typedef void svoid_t __attribute__((address_space(3)));

__device__ inline void gload16(const void* g, void* l) {
    __builtin_amdgcn_global_load_lds((gvoid_t*)g, (svoid_t*)l, 16, 0, 0);
}

__device__ inline u32 cvtpk_bf16(float lo, float hi) {
    u32 r;
    asm("v_cvt_pk_bf16_f32 %0, %1, %2" : "=v"(r) : "v"(lo), "v"(hi));
    return r;
}

// ---------------- f32 -> bf16 convert ----------------
__global__ __launch_bounds__(256) void f2b_kernel(const float* __restrict__ in,
                                                  bf16_t* __restrict__ out, int n8) {
    int i = blockIdx.x * 256 + threadIdx.x;
    if (i >= n8) return;
    const float4* p = reinterpret_cast<const float4*>(in) + (size_t)i * 2;
    float4 a = p[0], b = p[1];
    bf16x8 o;
    o[0] = (bf16_t)a.x; o[1] = (bf16_t)a.y; o[2] = (bf16_t)a.z; o[3] = (bf16_t)a.w;
    o[4] = (bf16_t)b.x; o[5] = (bf16_t)b.y; o[6] = (bf16_t)b.z; o[7] = (bf16_t)b.w;
    reinterpret_cast<bf16x8*>(out)[i] = o;
}

// ---------------- GEMM: C = A @ B^T (+bias, + mode-specific epilogue) -------
// A: [M][K] bf16, B: [N][K] bf16. 128x128 tile, BK=64, 4 waves, 16x16x32 MFMA.
// MODE 0: store bf16 (acc+bias)
// MODE 1: QKV: Q (col<512) -> qdst[row][col] * 1/16 (compact [16384][512])
//              K (512..1023) -> kdst chunked [bh][kt2][c=d/8][r=seq%32][e=d%8]
//              V (1024..)    -> vdst chunked [bh][kt2][kc=(seq%32)/8][d][e=seq%8]
// MODE 2: store f32  acc+bias + 0.5*(r1+r2)                 (final out-proj)
template <int MODE>
__global__ __launch_bounds__(256) void gemm_bt(const bf16_t* __restrict__ A,
                                               const bf16_t* __restrict__ Bw,
                                               const float* __restrict__ bias,
                                               void* __restrict__ Cout,
                                               const bf16_t* __restrict__ r1,
                                               const bf16_t* __restrict__ r2,
                                               bf16_t* __restrict__ qdst,
                                               bf16_t* __restrict__ kdst,
                                               bf16_t* __restrict__ vdst,
                                               int M, int N, int K) {
    __shared__ __align__(16) bf16_t As[128][64];
    __shared__ __align__(16) bf16_t Bs[128][64];
    const int tid = threadIdx.x, lane = tid & 63, w = tid >> 6;
    const int l16 = lane & 15, l4 = lane >> 4;
    const int wm = w >> 1, wn = w & 1;
    const size_t a0 = (size_t)blockIdx.y * 128;
    const size_t b0 = (size_t)blockIdx.x * 128;
    f32x4 acc[4][4] = {};
    const int srow = w * 32 + (lane >> 3);
    const int scol = (lane & 7) * 8;
    for (int kt = 0; kt < K; kt += 64) {
        __syncthreads();
#pragma unroll
        for (int i = 0; i < 4; ++i) {
            gload16(A + (a0 + srow + i * 8) * (size_t)K + kt + scol, &As[w * 32 + i * 8][0]);
            gload16(Bw + (b0 + srow + i * 8) * (size_t)K + kt + scol, &Bs[w * 32 + i * 8][0]);
        }
        __syncthreads();
#pragma unroll
        for (int kk = 0; kk < 2; ++kk) {
            bf16x8 af[4], bfr[4];
#pragma unroll
            for (int mi = 0; mi < 4; ++mi)
                af[mi] = *reinterpret_cast<const bf16x8*>(&As[wm * 64 + mi * 16 + l16][kk * 32 + l4 * 8]);
#pragma unroll
            for (int ni = 0; ni < 4; ++ni)
                bfr[ni] = *reinterpret_cast<const bf16x8*>(&Bs[wn * 64 + ni * 16 + l16][kk * 32 + l4 * 8]);
#pragma unroll
            for (int mi = 0; mi < 4; ++mi)
#pragma unroll
                for (int ni = 0; ni < 4; ++ni)
                    acc[mi][ni] = __builtin_amdgcn_mfma_f32_16x16x32_bf16(af[mi], bfr[ni], acc[mi][ni], 0, 0, 0);
        }
    }
#pragma unroll
    for (int mi = 0; mi < 4; ++mi) {
#pragma unroll
        for (int ni = 0; ni < 4; ++ni) {
            int col = (int)b0 + wn * 64 + ni * 16 + l16;
            float bs = bias[col];
            int row0 = (int)a0 + wm * 64 + mi * 16 + l4 * 4;
            float vv[4];
#pragma unroll
            for (int r = 0; r < 4; ++r) vv[r] = acc[mi][ni][r] + bs;
            if (MODE == 0) {
#pragma unroll
                for (int r = 0; r < 4; ++r)
                    ((bf16_t*)Cout)[(size_t)(row0 + r) * N + col] = (bf16_t)vv[r];
            } else if (MODE == 2) {
#pragma unroll
                for (int r = 0; r < 4; ++r) {
                    size_t idx = (size_t)(row0 + r) * N + col;
                    ((float*)Cout)[idx] = vv[r] + 0.5f * ((float)r1[idx] + (float)r2[idx]);
                }
            } else {
                if (col < 512) {
#pragma unroll
                    for (int r = 0; r < 4; ++r)
                        qdst[(size_t)(row0 + r) * 512 + col] = (bf16_t)(vv[r] * 0.0625f);
                } else if (col < 1024) {
                    int cc = col - 512, h = cc >> 8, d = cc & 255;
#pragma unroll
                    for (int r = 0; r < 4; ++r) {
                        int row = row0 + r;
                        int bh = (row >> 11) * 2 + h, seq = row & 2047;
                        kdst[((size_t)(bh * 64 + (seq >> 5))) * 8192 + (d >> 3) * 256 +
                             (seq & 31) * 8 + (d & 7)] = (bf16_t)vv[r];
                    }
                } else {
                    int cc = col - 1024, h = cc >> 8, d = cc & 255;
                    int bh = (row0 >> 11) * 2 + h, seq = row0 & 2047;
                    size_t idx = ((size_t)(bh * 64 + (seq >> 5))) * 8192 +
                                 ((seq >> 3) & 3) * 2048 + d * 8 + (seq & 7);
                    union { bf16_t h4[4]; uint2 u8; } pk;
#pragma unroll
                    for (int r = 0; r < 4; ++r) pk.h4[r] = (bf16_t)vv[r];
                    *reinterpret_cast<uint2*>(&vdst[idx]) = pk.u8;
                }
            }
        }
    }
}

// ---------------- gate = sigmoid(sum(rgb_p*event_p, axis=-1)) ----------------
__global__ __launch_bounds__(256) void gate_kernel(const bf16_t* __restrict__ rp,
                                                   const bf16_t* __restrict__ ep,
                                                   float* __restrict__ gate) {
    int row = blockIdx.x * 4 + (threadIdx.x >> 6);
    int lane = threadIdx.x & 63;
    bf16x8 a = reinterpret_cast<const bf16x8*>(rp + (size_t)row * 512)[lane];
    bf16x8 b = reinterpret_cast<const bf16x8*>(ep + (size_t)row * 512)[lane];
    float s = 0.f;
#pragma unroll
    for (int j = 0; j < 8; ++j) s += (float)a[j] * (float)b[j];
#pragma unroll
    for (int off = 32; off; off >>= 1) s += __shfl_xor(s, off, 64);
    if (lane == 0) gate[row] = 1.f / (1.f + __expf(-s));
}

// ---------------- flash attention v3 ----------------
// grid 512: bid = qb*32 + dir*16 + bh. 4 waves, wave owns 32 q rows, KVBLK=32.
// Double-buffered K/V via raw s_barrier + counted vmcnt pipeline (T3-minimum).
// K LDS [c=32][r=32][8e], V LDS [kc=4][d=256][8e]: all reads base+imm, conflict-free.
__global__ __launch_bounds__(256, 2) void attn_kernel(const bf16_t* __restrict__ qbr,
                                                      const bf16_t* __restrict__ qbe,
                                                      const bf16_t* __restrict__ kbr,
                                                      const bf16_t* __restrict__ kbe,
                                                      const bf16_t* __restrict__ vbr,
                                                      const bf16_t* __restrict__ vbe,
                                                      bf16_t* __restrict__ out0,
                                                      bf16_t* __restrict__ out1) {
    __shared__ __align__(16) bf16_t smem[32768];  // 2 bufs x (K 8192 + V 8192)
    const int bid = blockIdx.x;
    const int qb = bid >> 5;
    const int combo = bid & 31;
    const int dir = combo >> 4;
    const int bh = combo & 15;
    const int b = bh >> 1, h = bh & 1;
    const bf16_t* Qb = dir ? qbe : qbr;
    const bf16_t* Kc = dir ? kbr : kbe;
    const bf16_t* Vc = dir ? vbr : vbe;
    bf16_t* osrc = dir ? out1 : out0;
    const int tid = threadIdx.x;
    const int w = tid >> 6, l = tid & 63;
    const int l31 = l & 31, hi = l >> 5;
    const int q0w = qb * 128 + w * 32;

    // Q fragments (B-operand): lane holds Q[q0w + l31][dch*16 + hi*8 + j]
    const bf16_t* qp = Qb + ((size_t)(b * 2048 + q0w + l31)) * 512 + h * 256 + hi * 8;
    bf16x8 qf[16];
#pragma unroll
    for (int dch = 0; dch < 16; ++dch)
        qf[dch] = *reinterpret_cast<const bf16x8*>(qp + dch * 16);

    f32x16 O[8] = {};
    float mrun = -1e30f, lrun = 0.f;

    const bf16_t* kq = Kc + (size_t)bh * 524288 + (w * 2048 + l * 8);
    const bf16_t* vq = Vc + (size_t)bh * 524288 + (w * 2048 + l * 8);

#define STAGE(t, nb)                                              \
    do {                                                          \
        const bf16_t* ks_ = kq + (size_t)(t) * 8192;              \
        const bf16_t* vs_ = vq + (size_t)(t) * 8192;              \
        bf16_t* lk_ = &smem[(nb) * 16384 + w * 2048];             \
        bf16_t* lv_ = &smem[(nb) * 16384 + 8192 + w * 2048];      \
        gload16(ks_, lk_);                                        \
        gload16(ks_ + 512, lk_ + 512);                            \
        gload16(ks_ + 1024, lk_ + 1024);                          \
        gload16(ks_ + 1536, lk_ + 1536);                          \
        gload16(vs_, lv_);                                        \
        gload16(vs_ + 512, lv_ + 512);                            \
        gload16(vs_ + 1024, lv_ + 1024);                          \
        gload16(vs_ + 1536, lv_ + 1536);                          \
    } while (0)

    STAGE(0, 0);

    for (int kt2 = 0; kt2 < 64; ++kt2) {
        asm volatile("s_waitcnt vmcnt(0)" ::: "memory");
        __builtin_amdgcn_s_barrier();
        asm volatile("" ::: "memory");
        if (kt2 < 63) STAGE(kt2 + 1, (kt2 + 1) & 1);
        asm volatile("" ::: "memory");

        const int cb = kt2 & 1;
        const bf16_t* kb = &smem[cb * 16384 + hi * 256 + l31 * 8];
        const bf16_t* vb = &smem[cb * 16384 + 8192 + hi * 2048 + l31 * 8];

        // QK^T (swapped): st[r] = S[k = (r&3)+8*(r>>2)+4*hi][q = l31]
        f32x16 st = {};
#pragma unroll
        for (int dch = 0; dch < 16; ++dch) {
            bf16x8 kf = *reinterpret_cast<const bf16x8*>(kb + dch * 512);
            st = __builtin_amdgcn_mfma_f32_32x32x16_bf16(kf, qf[dch], st, 0, 0, 0);
        }

        // online softmax (lane-local, q = l31; partner lane ^32 holds other k half)
        float mx = -1e30f;
#pragma unroll
        for (int r = 0; r < 16; ++r) mx = fmaxf(mx, st[r]);
        mx = fmaxf(mx, __shfl_xor(mx, 32, 64));
        if (__any(mx - mrun > 8.f)) {
            float mnew = fmaxf(mrun, mx);
            float sc = __expf(mrun - mnew);
            mrun = mnew;
            lrun *= sc;
#pragma unroll
            for (int r = 0; r < 16; ++r) {
                int qr = (r & 3) + 8 * (r >> 2) + 4 * hi;
                float scr = __shfl(sc, qr, 64);
#pragma unroll
                for (int g = 0; g < 8; ++g) O[g][r] *= scr;
            }
        }
        float lsum = 0.f;
        u32 W[8];
#pragma unroll
        for (int m = 0; m < 8; ++m) {
            float plo = __expf(st[2 * m] - mrun);
            float phi_ = __expf(st[2 * m + 1] - mrun);
            lsum += plo + phi_;
            W[m] = cvtpk_bf16(plo, phi_);
        }
        lsum += __shfl_xor(lsum, 32, 64);
        lrun += lsum;

        // PV: A = P (2 shfl_xor(32) per 16-k step), B = V from LDS
#pragma unroll
        for (int s = 0; s < 2; ++s) {
            u32 t0 = hi ? W[4 * s] : W[4 * s + 2];
            u32 t1 = hi ? W[4 * s + 1] : W[4 * s + 3];
            u32 r0 = (u32)__shfl_xor((int)t0, 32, 64);
            u32 r1 = (u32)__shfl_xor((int)t1, 32, 64);
            union { u32 uw[4]; bf16x8 v; } a;
            a.uw[0] = hi ? r0 : W[4 * s];
            a.uw[1] = hi ? r1 : W[4 * s + 1];
            a.uw[2] = hi ? W[4 * s + 2] : r0;
            a.uw[3] = hi ? W[4 * s + 3] : r1;
#pragma unroll
            for (int g = 0; g < 8; ++g) {
                bf16x8 vf = *reinterpret_cast<const bf16x8*>(vb + s * 4096 + g * 256);
                O[g] = __builtin_amdgcn_mfma_f32_32x32x16_bf16(a.v, vf, O[g], 0, 0, 0);
            }
        }
    }
#undef STAGE

    // epilogue: normalize (lrun broadcast per q-row) and store
#pragma unroll
    for (int r = 0; r < 16; ++r) {
        int qr = (r & 3) + 8 * (r >> 2) + 4 * hi;
        float linv = 1.0f / __shfl(lrun, qr, 64);
        size_t rowoff = ((size_t)(b * 2048 + q0w + qr)) * 512 + h * 256 + l31;
#pragma unroll
        for (int g = 0; g < 8; ++g)
            osrc[rowoff + g * 32] = (bf16_t)(O[g][r] * linv);
    }
}

// ---------------- mix: gate*attn1 + (1-gate)*attn2 -> bf16 ----------------
__global__ __launch_bounds__(256) void mix_kernel(const bf16_t* __restrict__ a1,
                                                  const bf16_t* __restrict__ a2,
                                                  const float* __restrict__ gate,
                                                  bf16_t* __restrict__ outm) {
    int i = blockIdx.x * 256 + threadIdx.x;
    int m = i >> 6;
    float g = gate[m];
    bf16x8 x = reinterpret_cast<const bf16x8*>(a1)[i];
    bf16x8 y = reinterpret_cast<const bf16x8*>(a2)[i];
    bf16x8 o;
#pragma unroll
    for (int j = 0; j < 8; ++j) o[j] = (bf16_t)(g * (float)x[j] + (1.f - g) * (float)y[j]);
    reinterpret_cast<bf16x8*>(outm)[i] = o;
}

extern "C" void kernel_launch(void* const* d_in, const int* in_sizes, int n_in,
                              void* d_out, int out_size, void* d_ws, size_t ws_size,
                              hipStream_t stream) {
    const float* rgb = (const float*)d_in[0];
    const float* event = (const float*)d_in[1];
    const float* w_rgb = (const float*)d_in[2];
    const float* b_rgb = (const float*)d_in[3];
    const float* w_event = (const float*)d_in[4];
    const float* b_event = (const float*)d_in[5];
    const float* w_in = (const float*)d_in[6];
    const float* b_in = (const float*)d_in[7];
    const float* w_out = (const float*)d_in[8];
    const float* b_out = (const float*)d_in[9];
    float* out = (float*)d_out;

    const int M = 16384;  // B*S
    const size_t MB16 = (size_t)16 * 1024 * 1024;
    char* ws = (char*)d_ws;
    bf16_t* wrgb_bf = (bf16_t*)(ws + 0);
    bf16_t* wevt_bf = (bf16_t*)(ws + 524288);
    bf16_t* wout_bf = (bf16_t*)(ws + 1048576);
    bf16_t* win_bf = (bf16_t*)(ws + 1572864);
    float* gate = (float*)(ws + 3145728);
    bf16_t* bufA = (bf16_t*)(ws + 4194304);            // rgb bf16 -> attn out dir0
    bf16_t* bufB = (bf16_t*)(ws + 4194304 + MB16);     // event bf16 -> attn out dir1
    bf16_t* rgbp = (bf16_t*)(ws + 4194304 + 2 * MB16);
    bf16_t* evtp = (bf16_t*)(ws + 4194304 + 3 * MB16);
    bf16_t* qbr  = (bf16_t*)(ws + 4194304 + 4 * MB16);
    bf16_t* qbe  = (bf16_t*)(ws + 4194304 + 5 * MB16);
    bf16_t* kbr  = (bf16_t*)(ws + 4194304 + 6 * MB16);
    bf16_t* kbe  = (bf16_t*)(ws + 4194304 + 7 * MB16);
    bf16_t* vbr  = (bf16_t*)(ws + 4194304 + 8 * MB16);
    bf16_t* vbe  = (bf16_t*)(ws + 4194304 + 9 * MB16);
    bf16_t* mixed = (bf16_t*)(ws + 4194304 + 10 * MB16);

    dim3 blk(256);
    // converts
    f2b_kernel<<<4096, blk, 0, stream>>>(rgb, bufA, M * 512 / 8);
    f2b_kernel<<<4096, blk, 0, stream>>>(event, bufB, M * 512 / 8);
    f2b_kernel<<<128, blk, 0, stream>>>(w_rgb, wrgb_bf, 512 * 512 / 8);
    f2b_kernel<<<128, blk, 0, stream>>>(w_event, wevt_bf, 512 * 512 / 8);
    f2b_kernel<<<384, blk, 0, stream>>>(w_in, win_bf, 1536 * 512 / 8);
    f2b_kernel<<<128, blk, 0, stream>>>(w_out, wout_bf, 512 * 512 / 8);
    // input projections
    gemm_bt<0><<<dim3(4, 128), blk, 0, stream>>>(bufA, wrgb_bf, b_rgb, rgbp, nullptr, nullptr,
                                                 nullptr, nullptr, nullptr, M, 512, 512);
    gemm_bt<0><<<dim3(4, 128), blk, 0, stream>>>(bufB, wevt_bf, b_event, evtp, nullptr, nullptr,
                                                 nullptr, nullptr, nullptr, M, 512, 512);
    // gate
    gate_kernel<<<4096, blk, 0, stream>>>(rgbp, evtp, gate);
    // QKV projections -> Q compact + K/V chunked layouts (q-scale folded in)
    gemm_bt<1><<<dim3(12, 128), blk, 0, stream>>>(rgbp, win_bf, b_in, nullptr, nullptr, nullptr,
                                                  qbr, kbr, vbr, M, 1536, 512);
    gemm_bt<1><<<dim3(12, 128), blk, 0, stream>>>(evtp, win_bf, b_in, nullptr, nullptr, nullptr,
                                                  qbe, kbe, vbe, M, 1536, 512);
    // attention both directions
    attn_kernel<<<512, blk, 0, stream>>>(qbr, qbe, kbr, kbe, vbr, vbe, bufA, bufB);
    // gated mix
    mix_kernel<<<4096, blk, 0, stream>>>(bufA, bufB, gate, mixed);
    // final projection + residual, f32 out
    gemm_bt<2><<<dim3(4, 128), blk, 0, stream>>>(mixed, wout_bf, b_out, out, rgbp, evtp,
                                                 nullptr, nullptr, nullptr, M, 512, 512);
}